// Round 1
// 789.784 us; speedup vs baseline: 1.0452x; 1.0452x over previous
//
#include <hip/hip_runtime.h>
#include <hip/hip_bf16.h>

// Problem constants
#define NTOT 65536      // B*N
#define KNN  20
#define CKEEP 32        // kept candidates for exact re-rank (margin over 20)
#define CAPB 384        // candidate rows: 96 + 256 worst-case + 32 stash
#define BPAD 65         // padded row width -> scan bank = (j+q)%32
#define HEADROOM 96     // compact when cnt > HEADROOM
#define KROW 104        // bf16 kf row stride (67 dims + pad)

typedef __attribute__((ext_vector_type(4))) float f32x4;
typedef __attribute__((ext_vector_type(8))) short s16x8;

// ws layout (bytes): kfB bf16[65536][104] | normB f32[65536] | nbr i32
#define WS_NORM 13631488
#define WS_NBR  13893632

// k_knn LDS map (bytes)
#define SMEM_KSQ 53248      // ksB @0 (53248), ksq @53248 (1024); scratch region [0,58880)
#define SMEM_BUF 58880      // unsigned buf[384][65] = 99840
#define SMEM_CNT 158720     // int cnt[64]
#define SMEM_TAU 158976     // float tau[64]
#define SMEM_SZ  159232

__device__ __forceinline__ unsigned short f2bf_rne(float v){
  unsigned u = __float_as_uint(v);
  return (unsigned short)((u + 0x7FFFu + ((u >> 16) & 1u)) >> 16);
}

// ---------------------------------------------------------------------------
// k_prep: kf = [s(16), R^T v(48), pos(3)] -> bf16 rows (stride 104) + f32 norm
// ---------------------------------------------------------------------------
__global__ __launch_bounds__(256) void k_prep(const float* __restrict__ x,
        const float* __restrict__ pos, const float* __restrict__ lfr,
        unsigned short* __restrict__ kfB, float* __restrict__ normB){
  int n = blockIdx.x * 256 + threadIdx.x;
  const float* xr = x + n * 64;
  float R[9];
  #pragma unroll
  for (int j = 0; j < 9; j++) R[j] = lfr[n * 9 + j];
  float c[67];
  #pragma unroll
  for (int i = 0; i < 16; i++) c[i] = xr[i];
  #pragma unroll
  for (int k = 0; k < 16; k++){
    float v0 = xr[16 + 3*k], v1 = xr[17 + 3*k], v2 = xr[18 + 3*k];
    #pragma unroll
    for (int a = 0; a < 3; a++)
      c[16 + 3*k + a] = R[a] * v0 + R[3 + a] * v1 + R[6 + a] * v2;  // R^T v
  }
  #pragma unroll
  for (int a = 0; a < 3; a++) c[64 + a] = pos[n * 3 + a];
  float sq = 0.f;
  #pragma unroll
  for (int d = 0; d < 67; d++) sq += c[d] * c[d];
  __attribute__((aligned(16))) unsigned short row[KROW];
  #pragma unroll
  for (int d = 0; d < 67; d++) row[d] = f2bf_rne(c[d]);
  #pragma unroll
  for (int d = 67; d < KROW; d++) row[d] = 0;
  uint4* dst = (uint4*)(kfB + (size_t)n * KROW);
  const uint4* s4 = (const uint4*)row;
  #pragma unroll
  for (int i = 0; i < 13; i++) dst[i] = s4[i];
  normB[n] = sq;
}

// ---------------------------------------------------------------------------
// wave_compact: barrier-free exact top-32 for the wave's 8 queries.
// (called only by waves 0..7; one wave owns 8 queries)
// ---------------------------------------------------------------------------
__device__ __forceinline__ void wave_compact(unsigned (*buf)[BPAD],
    int* cnt, float* tau, int lane, int wv, int cmax){
  int q = (wv << 3) + (lane >> 3);
  int s = lane & 7;
  int cn = cnt[q];
  int mN = (cmax + 7) >> 3;          // chunk size (wave-uniform)
  int lo = s * mN;
  unsigned long long mask = 0ull;
  unsigned last = 0xFFFFFFFFu;
  #pragma unroll 1
  for (int r = 0; r < 32; r++){
    unsigned vmin = 0xFFFFFFFFu; int imin = -1;
    #pragma unroll 1
    for (int i = 0; i < mN; i++){
      int j = lo + i;
      unsigned v = (j < cn) ? buf[j][q] : 0xFFFFFFFFu;
      if (!((mask >> i) & 1ull) && v < vmin){ vmin = v; imin = i; }
    }
    unsigned bv = vmin;
    #pragma unroll
    for (int off = 1; off < 8; off <<= 1){
      unsigned ov = (unsigned)__shfl_xor((int)bv, off, 64);
      bv = (ov < bv) ? ov : bv;
    }
    if (vmin == bv && imin >= 0 && bv != 0xFFFFFFFFu) mask |= (1ull << (unsigned)imin);
    last = bv;
  }
  int kc = __popcll(mask);
  int incl = kc;
  #pragma unroll
  for (int d = 1; d < 8; d <<= 1){
    int t = __shfl_up(incl, d, 8);
    if (s >= d) incl += t;
  }
  int wr = cmax + (incl - kc);       // exclusive prefix over the 8 lanes
  #pragma unroll 1
  for (int i = 0; i < mN; i++){
    if ((mask >> i) & 1ull){
      buf[wr][q] = buf[lo + i][q];   // dest >= cmax > all sources: disjoint
      wr++;
    }
  }
  __builtin_amdgcn_s_waitcnt(0);     // stash visible within wave
  #pragma unroll
  for (int r = s; r < 32; r += 8){
    unsigned v = buf[cmax + r][q];
    buf[r][q] = v;
  }
  if (s == 0){ cnt[q] = 32; tau[q] = __uint_as_float(last & 0xFFFFC000u); }
  __builtin_amdgcn_s_waitcnt(0);
}

// ---------------------------------------------------------------------------
// k_knn: 1024 threads (16 waves). Each wave owns ONE 16-key column slice of
// the 256-key tile (halves per-wave work vs the 8-wave version) -> 4 waves/EU
// instead of 2: the latency-bound d2/tau/compact chains get 2x the TLP.
// Compaction still owned by waves 0..7 (8 queries each).
// ---------------------------------------------------------------------------
__global__ __launch_bounds__(1024, 4) void k_knn(
    const unsigned short* __restrict__ kfB, const float* __restrict__ normB,
    const float* __restrict__ x, const float* __restrict__ pos,
    const float* __restrict__ lfr, int* __restrict__ nbr){
  __shared__ __attribute__((aligned(16))) char smem[SMEM_SZ];
  unsigned short* ksB = (unsigned short*)(smem);
  float* ksq = (float*)(smem + SMEM_KSQ);
  unsigned (*buf)[BPAD] = (unsigned (*)[BPAD])(smem + SMEM_BUF);
  int* cnt = (int*)(smem + SMEM_CNT);
  float* tau = (float*)(smem + SMEM_TAU);

  int tid = threadIdx.x;
  int blk = blockIdx.x;
  int b = (blk & 7) >> 1;
  int w = ((blk >> 3) << 1) | (blk & 1);   // 0..63 within batch
  int bbase = b << 14;
  int q0 = w << 6;

  if (tid < 64){ cnt[tid] = 0; tau[tid] = 3.0e38f; }

  int lane = tid & 63;
  int wv = tid >> 6;                 // 0..15
  int l15 = lane & 15, quad = lane >> 4;

  auto issue_tile = [&](int tl){
    const char* gRow = (const char*)(kfB + (size_t)(bbase + (tl << 8)) * KROW);
    const char* gNrm = (const char*)(normB + bbase + (tl << 8));
    #pragma unroll
    for (int k2 = 0; k2 < 4; k2++){
      int i = tid + (k2 << 10);
      if (i < 3328){
        __builtin_amdgcn_global_load_lds(
            (const __attribute__((address_space(1))) void*)(gRow + (i << 4)),
            (__attribute__((address_space(3))) void*)((char*)ksB + (i << 4)),
            16, 0, 0);
      } else if (i < 3392){
        int j = i - 3328;
        __builtin_amdgcn_global_load_lds(
            (const __attribute__((address_space(1))) void*)(gNrm + (j << 4)),
            (__attribute__((address_space(3))) void*)((char*)ksq + (j << 4)),
            16, 0, 0);
      }
    }
  };

  s16x8 afr[4][3];
  float qsqv[4][4];
  #pragma unroll
  for (int mt = 0; mt < 4; mt++){
    int nodeA = bbase + ((q0 + mt * 16 + l15) << 2);
    #pragma unroll
    for (int ks = 0; ks < 3; ks++)
      afr[mt][ks] = *(const s16x8*)(kfB + (size_t)nodeA * KROW + ks * 32 + quad * 8);
    #pragma unroll
    for (int r = 0; r < 4; r++)
      qsqv[mt][r] = normB[bbase + ((q0 + mt * 16 + quad * 4 + r) << 2)];
  }

  issue_tile(0);
  __syncthreads();

  const unsigned long long SCHED =
      (1ull<<1)|(1ull<<3)|(1ull<<7)|(1ull<<15)|(1ull<<31)|(1ull<<47);

  for (int tile = 0; tile < 64; ++tile){
    int kbase = tile << 8;

    int ncol = (wv << 4) + l15;          // this wave's key column in the tile
    float ksqv = ksq[ncol];

    f32x4 acc[4];
    #pragma unroll
    for (int mt = 0; mt < 4; mt++) acc[mt] = (f32x4){0.f,0.f,0.f,0.f};

    #pragma unroll
    for (int ks = 0; ks < 3; ks++){
      s16x8 bfr = *(const s16x8*)(ksB + ncol * KROW + ks * 32 + quad * 8);
      #pragma unroll
      for (int mt = 0; mt < 4; mt++)
        acc[mt] = __builtin_amdgcn_mfma_f32_16x16x32_bf16(
            afr[mt][ks], bfr, acc[mt], 0, 0, 0);
    }

    int kidx = kbase + ncol;
    #pragma unroll
    for (int mt = 0; mt < 4; mt++){
      #pragma unroll
      for (int r = 0; r < 4; r++){
        int q = mt * 16 + quad * 4 + r;
        float d2 = fmaxf(qsqv[mt][r] + ksqv - 2.f * acc[mt][r], 0.f);
        if (d2 < tau[q]){
          int pp = atomicAdd(&cnt[q], 1);
          buf[pp][q] = ((__float_as_uint(d2) + 0x2000u) & 0xFFFFC000u) | (unsigned)kidx;
        }
      }
    }
    __syncthreads();   // B2: appends visible; ksB/ksq reads done
    if (tile < 63) issue_tile(tile + 1);

    if (wv < 8){
      int cmax = cnt[(wv << 3) + (lane >> 3)];
      #pragma unroll
      for (int off = 8; off < 64; off <<= 1){
        int o = __shfl_xor(cmax, off, 64);
        cmax = o > cmax ? o : cmax;
      }
      if (cmax > HEADROOM || ((SCHED >> tile) & 1ull))
        wave_compact(buf, cnt, tau, lane, wv, cmax);
    }
    __syncthreads();   // B1: drains DMA(t+1); compact results visible
  }
  if (wv < 8){
    int cmax = cnt[(wv << 3) + (lane >> 3)];
    #pragma unroll
    for (int off = 8; off < 64; off <<= 1){
      int o = __shfl_xor(cmax, off, 64);
      cmax = o > cmax ? o : cmax;
    }
    wave_compact(buf, cnt, tau, lane, wv, cmax);
  }
  __syncthreads();

  double* qkf = (double*)(smem);
  double* rrD = (double*)(smem + 34304);
  int*    rrI = (int*)(smem + 50688);

  {
    int t16 = tid & 15, q = tid >> 4;
    int node = bbase + ((q0 + q) << 2);
    const float* xr = x + node * 64;
    for (int dd = t16; dd < 67; dd += 16){
      double val;
      if (dd < 16) val = (double)xr[dd];
      else if (dd < 64){
        int r = dd - 16; int k = r / 3; int a = r - 3 * k;
        val = (double)lfr[node*9 + a]     * (double)xr[16 + 3*k]
            + (double)lfr[node*9 + 3 + a] * (double)xr[17 + 3*k]
            + (double)lfr[node*9 + 6 + a] * (double)xr[18 + 3*k];
      } else val = (double)pos[node*3 + (dd - 64)];
      qkf[q * 67 + dd] = val;
    }
  }
  __syncthreads();
  {
    int t16 = tid & 15, q = tid >> 4;
    for (int j = t16; j < CKEEP; j += 16){
      int idx = (int)(buf[j][q] & 0x3FFFu);
      int node = bbase + idx;
      const float* xr = x + node * 64;
      double R[9];
      #pragma unroll
      for (int t = 0; t < 9; t++) R[t] = (double)lfr[node * 9 + t];
      double d2 = 0.0;
      #pragma unroll
      for (int dd = 0; dd < 16; dd++){ double t = (double)xr[dd] - qkf[q*67 + dd]; d2 += t * t; }
      #pragma unroll
      for (int k = 0; k < 16; k++){
        double v0 = xr[16 + 3*k], v1 = xr[17 + 3*k], v2 = xr[18 + 3*k];
        #pragma unroll
        for (int a = 0; a < 3; a++){
          double val = R[a] * v0 + R[3 + a] * v1 + R[6 + a] * v2;
          double t = val - qkf[q*67 + 16 + 3*k + a]; d2 += t * t;
        }
      }
      #pragma unroll
      for (int a = 0; a < 3; a++){ double t = (double)pos[node*3 + a] - qkf[q*67 + 64 + a]; d2 += t * t; }
      rrD[q * CKEEP + j] = d2; rrI[q * CKEEP + j] = idx;
    }
  }
  __syncthreads();
  if (tid < 64){
    int qq = tid;
    int qid = (b << 12) + q0 + qq;
    #pragma unroll 1
    for (int s = 0; s < KNN; s++){
      double best = rrD[qq * CKEEP + s]; int bi = s;
      for (int t = s + 1; t < CKEEP; t++){
        double v = rrD[qq * CKEEP + t]; if (v < best){ best = v; bi = t; }
      }
      double tv = rrD[qq * CKEEP + bi]; rrD[qq * CKEEP + bi] = rrD[qq * CKEEP + s]; rrD[qq * CKEEP + s] = tv;
      int ti = rrI[qq * CKEEP + bi]; rrI[qq * CKEEP + bi] = rrI[qq * CKEEP + s]; rrI[qq * CKEEP + s] = ti;
      nbr[qid * KNN + s] = bbase + rrI[qq * CKEEP + s];
    }
  }
}

// ---------------------------------------------------------------------------
// k_mlp (MFMA rewrite): 8 queries/block = 160 edge-rows (10 m-tiles), 512 thr
// (8 waves, wave wv owns 16 output cols). bf16 MFMA both layers, fp32 acc.
// LDS k-blocked layouts [k/32][row][32] (16B-aligned b128 frags, 2-way banks).
// Max-over-20-edges fully in registers via compile-time query-boundary masks.
// ---------------------------------------------------------------------------
#define M_X   0         // xs f32[160][68] = 43520 ; later Wt2 bf16[4][128][32]
#define M_H   43520     // hB bf16[4][160][32] = 40960
#define M_A1  84480     // a1B bf16[4][160][32] = 40960 (early: nbrL/xdL/lfL overlay)
#define M_W   125440    // Wt1 bf16[4][128][32] = 32768
#define M_B1  158208    // b1 f32[128]
#define M_B2  158720    // b2 f32[128]
#define M_SZ  159232

__global__ __launch_bounds__(512) void k_mlp(const float* __restrict__ x,
    const float* __restrict__ lfr, const int* __restrict__ nbr,
    const float* __restrict__ W1, const float* __restrict__ b1,
    const float* __restrict__ W2, const float* __restrict__ b2,
    float* __restrict__ out){
  __shared__ __attribute__((aligned(16))) char smem[M_SZ];
  float* xsF = (float*)(smem + M_X);
  unsigned short* hB = (unsigned short*)(smem + M_H);
  unsigned short* a1B = (unsigned short*)(smem + M_A1);
  unsigned short* wt1 = (unsigned short*)(smem + M_W);
  unsigned short* wt2 = (unsigned short*)(smem + M_X);
  float* b1L = (float*)(smem + M_B1);
  float* b2L = (float*)(smem + M_B2);
  int*   nbrL = (int*)(smem + M_A1);            // overlay (dead before a1 writes)
  float* xdL  = (float*)(smem + M_A1 + 640);    // 8x64 f32
  float* lfL  = (float*)(smem + M_A1 + 2688);   // 8x9 f32

  int tid = threadIdx.x;
  int qid0 = blockIdx.x * 8;
  int lane = tid & 63, wv = tid >> 6;
  int l15 = lane & 15, quad = lane >> 4;

  // ---- init loads ----
  if (tid < 160) nbrL[tid] = nbr[qid0 * 20 + tid];
  {
    int q = tid >> 6, d = tid & 63;
    int qid = qid0 + q;
    int node = ((qid >> 12) << 14) + ((qid & 4095) << 2);
    xdL[q * 64 + d] = x[node * 64 + d];
  }
  if (tid < 72){
    int q = tid / 9, j = tid - 9 * q;
    int qid = qid0 + q;
    int node = ((qid >> 12) << 14) + ((qid & 4095) << 2);
    lfL[q * 9 + j] = lfr[node * 9 + j];
  }
  if (tid < 128){ b1L[tid] = b1[tid]; b2L[tid] = b2[tid]; }
  __syncthreads();

  // ---- gather x_src into xs (160 rows x 64 f32, stride 68) ----
  {
    int f4 = tid & 15;
    #pragma unroll
    for (int p = 0; p < 5; p++){
      int e = (tid >> 4) + (p << 5);
      float4 v = *(const float4*)&x[(size_t)nbrL[e] * 64 + (f4 << 2)];
      *(float4*)&xsF[e * 68 + (f4 << 2)] = v;
    }
  }
  __syncthreads();

  // ---- build h bf16 into hB [d>>5][e][d&31] ----
  {
    int d = tid & 127, eo = tid >> 7;   // eo 0..3
    int cls, kk = 0, aa = 0;
    if (d < 64) cls = 0;
    else { int dd = d - 64;
      if (dd < 16) cls = 1;
      else { cls = 2; int r = dd - 16; kk = (r * 21846) >> 16; aa = r - 3 * kk; } }
    int hoff = ((d >> 5) * 160) * 32 + (d & 31);
    #pragma unroll 4
    for (int p = 0; p < 40; p++){
      int e = eo + (p << 2);
      int q = (e * 3277) >> 16;       // e/20 for e<160
      float v;
      if (cls == 0) v = xdL[q * 64 + d];
      else if (cls == 1) v = xsF[e * 68 + (d - 64)] - xdL[q * 64 + (d - 64)];
      else {
        int base = 16 + 3 * kk;
        float u0 = xsF[e * 68 + base]     - xdL[q * 64 + base];
        float u1 = xsF[e * 68 + base + 1] - xdL[q * 64 + base + 1];
        float u2 = xsF[e * 68 + base + 2] - xdL[q * 64 + base + 2];
        v = lfL[q * 9 + aa * 3] * u0 + lfL[q * 9 + aa * 3 + 1] * u1 + lfL[q * 9 + aa * 3 + 2] * u2;
      }
      hB[hoff + e * 32] = f2bf_rne(v);
    }
  }
  __syncthreads();   // hB done; xs/xdL/lfL/nbrL dead

  // ---- stage Wt1 -> M_W, Wt2 -> M_X  (layout [k>>5][n][32], value W[k][n]) ----
  #pragma unroll 4
  for (int i = tid; i < 16384; i += 512){
    int k = i >> 7, n = i & 127;
    int a = ((k >> 5) * 128 + n) * 32 + (k & 31);
    wt1[a] = f2bf_rne(W1[i]);
    wt2[a] = f2bf_rne(W2[i]);
  }
  __syncthreads();   // weights visible

  // ---- layer 1: a1 = relu(h @ W1 + b1) ----
  {
    s16x8 bfr[4];
    #pragma unroll
    for (int ks = 0; ks < 4; ks++)
      bfr[ks] = *(const s16x8*)(wt1 + ((ks * 128 + (wv << 4) + l15) * 32 + (quad << 3)));
    float b1v = b1L[(wv << 4) + l15];
    int colhi = wv >> 1, collo = ((wv & 1) << 4) + l15;
    #pragma unroll
    for (int mt = 0; mt < 10; mt++){
      f32x4 acc = (f32x4){0.f, 0.f, 0.f, 0.f};
      #pragma unroll
      for (int ks = 0; ks < 4; ks++){
        s16x8 af = *(const s16x8*)(hB + ((ks * 160 + (mt << 4) + l15) * 32 + (quad << 3)));
        acc = __builtin_amdgcn_mfma_f32_16x16x32_bf16(af, bfr[ks], acc, 0, 0, 0);
      }
      #pragma unroll
      for (int r = 0; r < 4; r++){
        float v = fmaxf(acc[r] + b1v, 0.f);
        int row = (mt << 4) + (quad << 2) + r;
        a1B[(colhi * 160 + row) * 32 + collo] = f2bf_rne(v);
      }
    }
  }
  __syncthreads();   // a1 complete

  // ---- layer 2 + max over edges (registers only) ----
  {
    s16x8 bfr[4];
    #pragma unroll
    for (int ks = 0; ks < 4; ks++)
      bfr[ks] = *(const s16x8*)(wt2 + ((ks * 128 + (wv << 4) + l15) * 32 + (quad << 3)));
    float mxv[8];
    #pragma unroll
    for (int q = 0; q < 8; q++) mxv[q] = -3.0e38f;
    const int QA[10]  = {0,0,1,2,3,4,4,5,6,7};
    const int CUT[10] = {16,4,8,12,16,16,4,8,12,16};
    #pragma unroll
    for (int mt = 0; mt < 10; mt++){
      f32x4 acc = (f32x4){0.f, 0.f, 0.f, 0.f};
      #pragma unroll
      for (int ks = 0; ks < 4; ks++){
        s16x8 af = *(const s16x8*)(a1B + ((ks * 160 + (mt << 4) + l15) * 32 + (quad << 3)));
        acc = __builtin_amdgcn_mfma_f32_16x16x32_bf16(af, bfr[ks], acc, 0, 0, 0);
      }
      int qa = QA[mt], cut = CUT[mt];
      if (cut >= 16){
        #pragma unroll
        for (int r = 0; r < 4; r++) mxv[qa] = fmaxf(mxv[qa], acc[r]);
      } else {
        #pragma unroll
        for (int r = 0; r < 4; r++){
          int lr = (quad << 2) + r;
          bool toA = lr < cut;
          mxv[qa]     = fmaxf(mxv[qa],     toA ? acc[r] : -3.0e38f);
          mxv[qa + 1] = fmaxf(mxv[qa + 1], toA ? -3.0e38f : acc[r]);
        }
      }
    }
    // combine across quads (rows) -- all lanes end with full per-col max
    #pragma unroll
    for (int q = 0; q < 8; q++){
      float v = mxv[q];
      v = fmaxf(v, __shfl_xor(v, 16, 64));
      v = fmaxf(v, __shfl_xor(v, 32, 64));
      mxv[q] = v;
    }
    if (quad == 0){
      int col = (wv << 4) + l15;
      float b2v = b2L[col];
      #pragma unroll
      for (int q = 0; q < 8; q++)
        out[(size_t)(qid0 + q) * 128 + col] = mxv[q] + b2v;
    }
  }
}

// ---------------------------------------------------------------------------
// k_tail: pos[idx], batch[idx], lframes[idx] as fp32 at flat offsets.
// ---------------------------------------------------------------------------
__global__ __launch_bounds__(256) void k_tail(const float* __restrict__ pos,
    const float* __restrict__ lfr, float* __restrict__ out){
  int q = blockIdx.x * 256 + threadIdx.x;   // 0..16383
  int b = q >> 12;
  int node = (b << 14) + ((q & 4095) << 2);
  float* o_pos = out + 2097152;    // 16384*128
  float* o_bat = out + 2146304;    // + 16384*3
  float* o_lf  = out + 2162688;    // + 16384
  #pragma unroll
  for (int j = 0; j < 3; j++) o_pos[q * 3 + j] = pos[node * 3 + j];
  o_bat[q] = (float)b;
  #pragma unroll
  for (int j = 0; j < 9; j++) o_lf[q * 9 + j] = lfr[node * 9 + j];
}

extern "C" void kernel_launch(void* const* d_in, const int* in_sizes, int n_in,
                              void* d_out, int out_size, void* d_ws, size_t ws_size,
                              hipStream_t stream){
  const float* x   = (const float*)d_in[0];
  const float* pos = (const float*)d_in[1];
  const float* lfr = (const float*)d_in[2];
  // d_in[3] = batch (recomputed analytically)
  const float* W1  = (const float*)d_in[4];
  const float* b1  = (const float*)d_in[5];
  const float* W2  = (const float*)d_in[6];
  const float* b2  = (const float*)d_in[7];

  unsigned short* kfB = (unsigned short*)d_ws;
  float* normB = (float*)((char*)d_ws + WS_NORM);
  int*   nbr   = (int*)((char*)d_ws + WS_NBR);
  float* out = (float*)d_out;

  hipLaunchKernelGGL(k_prep, dim3(256),  dim3(256),  0, stream, x, pos, lfr, kfB, normB);
  hipLaunchKernelGGL(k_knn,  dim3(256),  dim3(1024), 0, stream, kfB, normB, x, pos, lfr, nbr);
  hipLaunchKernelGGL(k_mlp,  dim3(2048), dim3(512),  0, stream, x, lfr, nbr, W1, b1, W2, b2, out);
  hipLaunchKernelGGL(k_tail, dim3(64),   dim3(256),  0, stream, pos, lfr, out);
}

// Round 2
// 702.042 us; speedup vs baseline: 1.1758x; 1.1250x over previous
//
#include <hip/hip_runtime.h>
#include <hip/hip_bf16.h>

// Problem constants
#define NTOT 65536      // B*N
#define KNN  20
#define KROW 104        // bf16 kf row stride (67 dims + pad)

typedef __attribute__((ext_vector_type(4))) float f32x4;
typedef __attribute__((ext_vector_type(8))) short s16x8;

// ws layout (bytes): kfB bf16[65536][104] | normB f32[65536] | nbr i32
#define WS_NORM 13631488
#define WS_NBR  13893632

// ---- k_knn LDS map (bytes) ----
// buf: 144 rows x 257 dwords (256 columns + 1 pad for bank spread) = 148032
// col = qLocal*4 + kq   (qLocal 0..63 within block, kq = key quarter 0..3)
#define ROWS 144
#define CSTR 257
#define OFF_CNT  148032     // int cnt[256]
#define OFF_TAUG 149056     // unsigned tauG[64]
#define OFF_MG   149312     // unsigned mg[64*32]
#define KNN_SMEM 157504
#define THRESH 64           // compact a column when cnt > THRESH (max cn 96 <= 128)

__device__ __forceinline__ unsigned short f2bf_rne(float v){
  unsigned u = __float_as_uint(v);
  return (unsigned short)((u + 0x7FFFu + ((u >> 16) & 1u)) >> 16);
}

// ---------------------------------------------------------------------------
// k_prep: kf = [s(16), R^T v(48), pos(3)] -> bf16 rows (stride 104) + f32 norm
// ---------------------------------------------------------------------------
__global__ __launch_bounds__(256) void k_prep(const float* __restrict__ x,
        const float* __restrict__ pos, const float* __restrict__ lfr,
        unsigned short* __restrict__ kfB, float* __restrict__ normB){
  int n = blockIdx.x * 256 + threadIdx.x;
  const float* xr = x + n * 64;
  float R[9];
  #pragma unroll
  for (int j = 0; j < 9; j++) R[j] = lfr[n * 9 + j];
  float c[67];
  #pragma unroll
  for (int i = 0; i < 16; i++) c[i] = xr[i];
  #pragma unroll
  for (int k = 0; k < 16; k++){
    float v0 = xr[16 + 3*k], v1 = xr[17 + 3*k], v2 = xr[18 + 3*k];
    #pragma unroll
    for (int a = 0; a < 3; a++)
      c[16 + 3*k + a] = R[a] * v0 + R[3 + a] * v1 + R[6 + a] * v2;  // R^T v
  }
  #pragma unroll
  for (int a = 0; a < 3; a++) c[64 + a] = pos[n * 3 + a];
  float sq = 0.f;
  #pragma unroll
  for (int d = 0; d < 67; d++) sq += c[d] * c[d];
  __attribute__((aligned(16))) unsigned short row[KROW];
  #pragma unroll
  for (int d = 0; d < 67; d++) row[d] = f2bf_rne(c[d]);
  #pragma unroll
  for (int d = 67; d < KROW; d++) row[d] = 0;
  uint4* dst = (uint4*)(kfB + (size_t)n * KROW);
  const uint4* s4 = (const uint4*)row;
  #pragma unroll
  for (int i = 0; i < 13; i++) dst[i] = s4[i];
  normB[n] = sq;
}

// ---------------------------------------------------------------------------
// col_compact: exact top-32 (by full 32-bit packed value) of one column with
// cn (<=128) entries. 32-round ballot binary search for the 32nd smallest,
// then ballot-prefix filter rewrite. Wave-local, no barriers.
// ---------------------------------------------------------------------------
__device__ __forceinline__ unsigned col_compact(unsigned* buf, int* cnt,
    int col, int cn, int lane){
  unsigned e0 = (lane < cn) ? buf[lane * CSTR + col] : 0xFFFFFFFFu;
  unsigned e1 = (lane + 64 < cn) ? buf[(lane + 64) * CSTR + col] : 0xFFFFFFFFu;
  unsigned T = 0;
  #pragma unroll 1
  for (int b = 31; b >= 0; --b){
    unsigned cand = T | (1u << b);
    int c = __popcll(__ballot(e0 < cand)) + __popcll(__ballot(e1 < cand));
    if (c <= 31) T = cand;   // largest U with count(<U)<=31  ==> 32nd smallest
  }
  unsigned long long m0 = __ballot(e0 <= T);
  unsigned long long m1 = __ballot(e1 <= T);
  int b1 = __popcll(m0);
  unsigned long long ltm = (1ull << lane) - 1ull;
  if (e0 <= T) buf[__popcll(m0 & ltm) * CSTR + col] = e0;
  if (e1 <= T) buf[(b1 + __popcll(m1 & ltm)) * CSTR + col] = e1;
  if (lane == 0) cnt[col] = 32;
  return T;
}

// ---------------------------------------------------------------------------
// k_knn: barrier-free scan. 256 blocks x 1024 thr (16 waves). Wave (wq,kq):
// 16 queries (wq) x 4096 keys (quarter kq). Keys read direct from global
// (L2-resident; block->batch = blk&3 keeps each XCD on one 3.4MB slice).
// Private candidate columns, shared monotone tauG via atomicMin. MFMA d2.
// ---------------------------------------------------------------------------
__global__ __launch_bounds__(1024, 4) void k_knn(
    const unsigned short* __restrict__ kfB, const float* __restrict__ normB,
    const float* __restrict__ x, const float* __restrict__ pos,
    const float* __restrict__ lfr, int* __restrict__ nbr){
  __shared__ __attribute__((aligned(16))) char smem[KNN_SMEM];
  unsigned* buf = (unsigned*)smem;
  int* cnt = (int*)(smem + OFF_CNT);
  unsigned* tauG = (unsigned*)(smem + OFF_TAUG);
  unsigned* mg = (unsigned*)(smem + OFF_MG);

  int tid = threadIdx.x;
  int blk = blockIdx.x;
  int b = blk & 3;                 // batch; XCD (blk%8) serves one batch slice
  int qloc0 = (blk >> 2) << 6;     // query block within batch: 0..4032
  int bbase = b << 14;

  if (tid < 256) cnt[tid] = 0;
  if (tid < 64) tauG[tid] = 0x7F7FC000u;   // huge float (not NaN)

  int lane = tid & 63;
  int wv = tid >> 6;               // 0..15
  int wq = wv >> 2;                // query sub-group 0..3
  int kq = wv & 3;                 // key quarter 0..3
  int l15 = lane & 15, quad = lane >> 4;
  int colB = (wq << 6) + kq;       // col = colB + quad*16 + r*4

  // A fragments: wave's 16 queries
  int qloc = qloc0 + (wq << 4);
  s16x8 af[3];
  {
    int nodeA = bbase + ((qloc + l15) << 2);
    const unsigned short* ap = kfB + (size_t)nodeA * KROW + quad * 8;
    af[0] = *(const s16x8*)(ap);
    af[1] = *(const s16x8*)(ap + 32);
    af[2] = *(const s16x8*)(ap + 64);
  }
  float qsq[4];
  #pragma unroll
  for (int r = 0; r < 4; r++)
    qsq[r] = normB[bbase + ((qloc + (quad << 2) + r) << 2)];

  float tauR[4] = {3.0e38f, 3.0e38f, 3.0e38f, 3.0e38f};

  // key stream pointers (lane l15 -> key (kq*4096 + g*16 + l15))
  const unsigned short* kp = kfB + (size_t)(bbase + (kq << 12) + l15) * KROW + quad * 8;
  const float* np = normB + (bbase + (kq << 12) + l15);

  __syncthreads();   // cnt/tauG init visible

  s16x8 cA[3], cB[3];
  float nA, nB;
  #define LOADK(dst, dn) do { \
      dst[0] = *(const s16x8*)(kp); \
      dst[1] = *(const s16x8*)(kp + 32); \
      dst[2] = *(const s16x8*)(kp + 64); \
      dn = *np; kp += 16 * KROW; np += 16; } while (0)

  auto comp = [&](const s16x8 bf[3], float ksqv, float d2v[4]){
    f32x4 acc = (f32x4){0.f, 0.f, 0.f, 0.f};
    acc = __builtin_amdgcn_mfma_f32_16x16x32_bf16(af[0], bf[0], acc, 0, 0, 0);
    acc = __builtin_amdgcn_mfma_f32_16x16x32_bf16(af[1], bf[1], acc, 0, 0, 0);
    acc = __builtin_amdgcn_mfma_f32_16x16x32_bf16(af[2], bf[2], acc, 0, 0, 0);
    #pragma unroll
    for (int r = 0; r < 4; r++)
      d2v[r] = fmaxf(qsq[r] + ksqv - 2.f * acc[r], 0.f);
  };

  auto seed = [&](const float d2v[4], int g){
    int kidx = (kq << 12) + (g << 4) + l15;
    #pragma unroll
    for (int r = 0; r < 4; r++){
      unsigned pk = ((__float_as_uint(d2v[r]) + 0x2000u) & 0xFFFFC000u) | (unsigned)kidx;
      buf[((g << 4) + l15) * CSTR + colB + (quad << 4) + (r << 2)] = pk;
    }
  };

  auto process = [&](const float d2v[4], int g){
    bool p[4];
    #pragma unroll
    for (int r = 0; r < 4; r++) p[r] = d2v[r] < tauR[r];
    if (__any(p[0] | p[1] | p[2] | p[3])){
      int kidx = (kq << 12) + (g << 4) + l15;
      #pragma unroll
      for (int r = 0; r < 4; r++){
        unsigned long long m = __ballot(p[r]);
        if (m){
          int lo = (int)((m >> (quad << 4)) & 0xFFFFull);
          int colr = colB + (quad << 4) + (r << 2);
          int leader = (quad << 4) + (__ffs(lo) - 1);
          int src = lo ? leader : lane;
          int base = 0;
          if (lo && (lane == leader)) base = atomicAdd(&cnt[colr], __popc(lo));
          base = __shfl(base, src, 64);
          if (p[r]){
            int pre = __popc(lo & ((1 << l15) - 1));
            unsigned pk = ((__float_as_uint(d2v[r]) + 0x2000u) & 0xFFFFC000u) | (unsigned)kidx;
            buf[(base + pre) * CSTR + colr] = pk;
          }
        }
      }
    }
  };

  // ---- prologue: groups 0,1 seeded unconditionally (rows g*16+l15) ----
  float d2v[4];
  LOADK(cA, nA);            // g=0
  LOADK(cB, nB);            // g=1
  comp(cA, nA, d2v);
  seed(d2v, 0);
  LOADK(cA, nA);            // prefetch g=2
  comp(cB, nB, d2v);
  seed(d2v, 1);
  LOADK(cB, nB);            // prefetch g=3
  if (lane < 16) cnt[colB + (lane << 2)] = 32;

  // ---- main scan: pairs of groups, 1-ahead register prefetch ----
  #pragma unroll 1
  for (int g = 2; g < 256; g += 2){
    comp(cA, nA, d2v);
    LOADK(cA, nA);          // prefetch g+2 (tail overrun reads valid ws bytes)
    process(d2v, g);
    comp(cB, nB, d2v);
    LOADK(cB, nB);          // prefetch g+3
    process(d2v, g + 1);

    // per-pair: compact any over-threshold column; refresh reg tau
    int cj = cnt[colB + ((lane & 15) << 2)];
    unsigned long long need = __ballot((lane < 16) && (cj > THRESH));
    while (need){
      int j2 = __ffsll((unsigned long long)need) - 1;
      need &= need - 1;
      int col = colB + (j2 << 2);
      int cn = __shfl(cj, j2, 64);
      unsigned T = col_compact(buf, cnt, col, cn, lane);
      if (lane == 0) atomicMin(&tauG[(wq << 4) + j2], T);
    }
    #pragma unroll
    for (int r = 0; r < 4; r++)
      tauR[r] = __uint_as_float(tauG[(wq << 4) + (quad << 2) + r] & 0xFFFFC000u);
  }

  // ---- final per-column exact top-32 ----
  {
    int cj = cnt[colB + ((lane & 15) << 2)];
    unsigned long long need = __ballot((lane < 16) && (cj > 32));
    while (need){
      int j2 = __ffsll((unsigned long long)need) - 1;
      need &= need - 1;
      int col = colB + (j2 << 2);
      int cn = __shfl(cj, j2, 64);
      col_compact(buf, cnt, col, cn, lane);
    }
  }
  __syncthreads();

  // ---- per-query merge of 4 columns -> exact top-32 into mg ----
  #pragma unroll 1
  for (int s = 0; s < 4; s++){
    int q = (wv << 2) + s;           // 0..63
    int c0 = cnt[(q << 2) + 0], c1 = cnt[(q << 2) + 1];
    int c2 = cnt[(q << 2) + 2], c3 = cnt[(q << 2) + 3];
    int t1 = c0 + c1, t2 = t1 + c2, tot = t2 + c3;
    auto fetch = [&](int i)->unsigned{
      int cc, rr;
      if (i < c0){ cc = 0; rr = i; }
      else if (i < t1){ cc = 1; rr = i - c0; }
      else if (i < t2){ cc = 2; rr = i - t1; }
      else { cc = 3; rr = i - t2; }
      return buf[rr * CSTR + (q << 2) + cc];
    };
    unsigned e0 = (lane < tot) ? fetch(lane) : 0xFFFFFFFFu;
    unsigned e1 = (lane + 64 < tot) ? fetch(lane + 64) : 0xFFFFFFFFu;
    unsigned T = 0;
    #pragma unroll 1
    for (int bb = 31; bb >= 0; --bb){
      unsigned cand = T | (1u << bb);
      int c = __popcll(__ballot(e0 < cand)) + __popcll(__ballot(e1 < cand));
      if (c <= 31) T = cand;
    }
    unsigned long long m0 = __ballot(e0 <= T);
    unsigned long long m1 = __ballot(e1 <= T);
    int b1 = __popcll(m0);
    unsigned long long ltm = (1ull << lane) - 1ull;
    int p0 = __popcll(m0 & ltm);
    int p1 = b1 + __popcll(m1 & ltm);
    if ((e0 <= T) && (p0 < 32)) mg[(q << 5) + p0] = e0;
    if ((e1 <= T) && (p1 < 32)) mg[(q << 5) + p1] = e1;
  }
  __syncthreads();

  // ---- fp64 exact rerank of 32 candidates/query (overlays buf region) ----
  double* qkf = (double*)(smem);
  double* rrD = (double*)(smem + 34304);
  int*    rrI = (int*)(smem + 50688);

  {
    int t16 = tid & 15, q = tid >> 4;
    int node = bbase + ((qloc0 + q) << 2);
    const float* xr = x + node * 64;
    for (int dd = t16; dd < 67; dd += 16){
      double val;
      if (dd < 16) val = (double)xr[dd];
      else if (dd < 64){
        int r = dd - 16; int k = r / 3; int a = r - 3 * k;
        val = (double)lfr[node*9 + a]     * (double)xr[16 + 3*k]
            + (double)lfr[node*9 + 3 + a] * (double)xr[17 + 3*k]
            + (double)lfr[node*9 + 6 + a] * (double)xr[18 + 3*k];
      } else val = (double)pos[node*3 + (dd - 64)];
      qkf[q * 67 + dd] = val;
    }
  }
  __syncthreads();
  {
    int t16 = tid & 15, q = tid >> 4;
    for (int j = t16; j < 32; j += 16){
      int idx = (int)(mg[(q << 5) + j] & 0x3FFFu);
      int node = bbase + idx;
      const float* xr = x + node * 64;
      double R[9];
      #pragma unroll
      for (int t = 0; t < 9; t++) R[t] = (double)lfr[node * 9 + t];
      double d2 = 0.0;
      #pragma unroll
      for (int dd = 0; dd < 16; dd++){ double t = (double)xr[dd] - qkf[q*67 + dd]; d2 += t * t; }
      #pragma unroll
      for (int k = 0; k < 16; k++){
        double v0 = xr[16 + 3*k], v1 = xr[17 + 3*k], v2 = xr[18 + 3*k];
        #pragma unroll
        for (int a = 0; a < 3; a++){
          double val = R[a] * v0 + R[3 + a] * v1 + R[6 + a] * v2;
          double t = val - qkf[q*67 + 16 + 3*k + a]; d2 += t * t;
        }
      }
      #pragma unroll
      for (int a = 0; a < 3; a++){ double t = (double)pos[node*3 + a] - qkf[q*67 + 64 + a]; d2 += t * t; }
      rrD[q * 32 + j] = d2; rrI[q * 32 + j] = idx;
    }
  }
  __syncthreads();
  if (tid < 64){
    int qq = tid;
    int qid = (b << 12) + qloc0 + qq;
    #pragma unroll 1
    for (int s = 0; s < KNN; s++){
      double best = rrD[qq * 32 + s]; int bi = s;
      for (int t = s + 1; t < 32; t++){
        double v = rrD[qq * 32 + t]; if (v < best){ best = v; bi = t; }
      }
      double tv = rrD[qq * 32 + bi]; rrD[qq * 32 + bi] = rrD[qq * 32 + s]; rrD[qq * 32 + s] = tv;
      int ti = rrI[qq * 32 + bi]; rrI[qq * 32 + bi] = rrI[qq * 32 + s]; rrI[qq * 32 + s] = ti;
      nbr[qid * KNN + s] = bbase + rrI[qq * 32 + s];
    }
  }
}

// ---------------------------------------------------------------------------
// k_mlp (MFMA rewrite): 8 queries/block = 160 edge-rows (10 m-tiles), 512 thr
// (8 waves, wave wv owns 16 output cols). bf16 MFMA both layers, fp32 acc.
// LDS k-blocked layouts [k/32][row][32] (16B-aligned b128 frags, 2-way banks).
// Max-over-20-edges fully in registers via compile-time query-boundary masks.
// ---------------------------------------------------------------------------
#define M_X   0         // xs f32[160][68] = 43520 ; later Wt2 bf16[4][128][32]
#define M_H   43520     // hB bf16[4][160][32] = 40960
#define M_A1  84480     // a1B bf16[4][160][32] = 40960 (early: nbrL/xdL/lfL overlay)
#define M_W   125440    // Wt1 bf16[4][128][32] = 32768
#define M_B1  158208    // b1 f32[128]
#define M_B2  158720    // b2 f32[128]
#define M_SZ  159232

__global__ __launch_bounds__(512) void k_mlp(const float* __restrict__ x,
    const float* __restrict__ lfr, const int* __restrict__ nbr,
    const float* __restrict__ W1, const float* __restrict__ b1,
    const float* __restrict__ W2, const float* __restrict__ b2,
    float* __restrict__ out){
  __shared__ __attribute__((aligned(16))) char smem[M_SZ];
  float* xsF = (float*)(smem + M_X);
  unsigned short* hB = (unsigned short*)(smem + M_H);
  unsigned short* a1B = (unsigned short*)(smem + M_A1);
  unsigned short* wt1 = (unsigned short*)(smem + M_W);
  unsigned short* wt2 = (unsigned short*)(smem + M_X);
  float* b1L = (float*)(smem + M_B1);
  float* b2L = (float*)(smem + M_B2);
  int*   nbrL = (int*)(smem + M_A1);            // overlay (dead before a1 writes)
  float* xdL  = (float*)(smem + M_A1 + 640);    // 8x64 f32
  float* lfL  = (float*)(smem + M_A1 + 2688);   // 8x9 f32

  int tid = threadIdx.x;
  int qid0 = blockIdx.x * 8;
  int lane = tid & 63, wv = tid >> 6;
  int l15 = lane & 15, quad = lane >> 4;

  // ---- init loads ----
  if (tid < 160) nbrL[tid] = nbr[qid0 * 20 + tid];
  {
    int q = tid >> 6, d = tid & 63;
    int qid = qid0 + q;
    int node = ((qid >> 12) << 14) + ((qid & 4095) << 2);
    xdL[q * 64 + d] = x[node * 64 + d];
  }
  if (tid < 72){
    int q = tid / 9, j = tid - 9 * q;
    int qid = qid0 + q;
    int node = ((qid >> 12) << 14) + ((qid & 4095) << 2);
    lfL[q * 9 + j] = lfr[node * 9 + j];
  }
  if (tid < 128){ b1L[tid] = b1[tid]; b2L[tid] = b2[tid]; }
  __syncthreads();

  // ---- gather x_src into xs (160 rows x 64 f32, stride 68) ----
  {
    int f4 = tid & 15;
    #pragma unroll
    for (int p = 0; p < 5; p++){
      int e = (tid >> 4) + (p << 5);
      float4 v = *(const float4*)&x[(size_t)nbrL[e] * 64 + (f4 << 2)];
      *(float4*)&xsF[e * 68 + (f4 << 2)] = v;
    }
  }
  __syncthreads();

  // ---- build h bf16 into hB [d>>5][e][d&31] ----
  {
    int d = tid & 127, eo = tid >> 7;   // eo 0..3
    int cls, kk = 0, aa = 0;
    if (d < 64) cls = 0;
    else { int dd = d - 64;
      if (dd < 16) cls = 1;
      else { cls = 2; int r = dd - 16; kk = (r * 21846) >> 16; aa = r - 3 * kk; } }
    int hoff = ((d >> 5) * 160) * 32 + (d & 31);
    #pragma unroll 4
    for (int p = 0; p < 40; p++){
      int e = eo + (p << 2);
      int q = (e * 3277) >> 16;       // e/20 for e<160
      float v;
      if (cls == 0) v = xdL[q * 64 + d];
      else if (cls == 1) v = xsF[e * 68 + (d - 64)] - xdL[q * 64 + (d - 64)];
      else {
        int base = 16 + 3 * kk;
        float u0 = xsF[e * 68 + base]     - xdL[q * 64 + base];
        float u1 = xsF[e * 68 + base + 1] - xdL[q * 64 + base + 1];
        float u2 = xsF[e * 68 + base + 2] - xdL[q * 64 + base + 2];
        v = lfL[q * 9 + aa * 3] * u0 + lfL[q * 9 + aa * 3 + 1] * u1 + lfL[q * 9 + aa * 3 + 2] * u2;
      }
      hB[hoff + e * 32] = f2bf_rne(v);
    }
  }
  __syncthreads();   // hB done; xs/xdL/lfL/nbrL dead

  // ---- stage Wt1 -> M_W, Wt2 -> M_X  (layout [k>>5][n][32], value W[k][n]) ----
  #pragma unroll 4
  for (int i = tid; i < 16384; i += 512){
    int k = i >> 7, n = i & 127;
    int a = ((k >> 5) * 128 + n) * 32 + (k & 31);
    wt1[a] = f2bf_rne(W1[i]);
    wt2[a] = f2bf_rne(W2[i]);
  }
  __syncthreads();   // weights visible

  // ---- layer 1: a1 = relu(h @ W1 + b1) ----
  {
    s16x8 bfr[4];
    #pragma unroll
    for (int ks = 0; ks < 4; ks++)
      bfr[ks] = *(const s16x8*)(wt1 + ((ks * 128 + (wv << 4) + l15) * 32 + (quad << 3)));
    float b1v = b1L[(wv << 4) + l15];
    int colhi = wv >> 1, collo = ((wv & 1) << 4) + l15;
    #pragma unroll
    for (int mt = 0; mt < 10; mt++){
      f32x4 acc = (f32x4){0.f, 0.f, 0.f, 0.f};
      #pragma unroll
      for (int ks = 0; ks < 4; ks++){
        s16x8 af = *(const s16x8*)(hB + ((ks * 160 + (mt << 4) + l15) * 32 + (quad << 3)));
        acc = __builtin_amdgcn_mfma_f32_16x16x32_bf16(af, bfr[ks], acc, 0, 0, 0);
      }
      #pragma unroll
      for (int r = 0; r < 4; r++){
        float v = fmaxf(acc[r] + b1v, 0.f);
        int row = (mt << 4) + (quad << 2) + r;
        a1B[(colhi * 160 + row) * 32 + collo] = f2bf_rne(v);
      }
    }
  }
  __syncthreads();   // a1 complete

  // ---- layer 2 + max over edges (registers only) ----
  {
    s16x8 bfr[4];
    #pragma unroll
    for (int ks = 0; ks < 4; ks++)
      bfr[ks] = *(const s16x8*)(wt2 + ((ks * 128 + (wv << 4) + l15) * 32 + (quad << 3)));
    float mxv[8];
    #pragma unroll
    for (int q = 0; q < 8; q++) mxv[q] = -3.0e38f;
    const int QA[10]  = {0,0,1,2,3,4,4,5,6,7};
    const int CUT[10] = {16,4,8,12,16,16,4,8,12,16};
    #pragma unroll
    for (int mt = 0; mt < 10; mt++){
      f32x4 acc = (f32x4){0.f, 0.f, 0.f, 0.f};
      #pragma unroll
      for (int ks = 0; ks < 4; ks++){
        s16x8 af = *(const s16x8*)(a1B + ((ks * 160 + (mt << 4) + l15) * 32 + (quad << 3)));
        acc = __builtin_amdgcn_mfma_f32_16x16x32_bf16(af, bfr[ks], acc, 0, 0, 0);
      }
      int qa = QA[mt], cut = CUT[mt];
      if (cut >= 16){
        #pragma unroll
        for (int r = 0; r < 4; r++) mxv[qa] = fmaxf(mxv[qa], acc[r]);
      } else {
        #pragma unroll
        for (int r = 0; r < 4; r++){
          int lr = (quad << 2) + r;
          bool toA = lr < cut;
          mxv[qa]     = fmaxf(mxv[qa],     toA ? acc[r] : -3.0e38f);
          mxv[qa + 1] = fmaxf(mxv[qa + 1], toA ? -3.0e38f : acc[r]);
        }
      }
    }
    // combine across quads (rows) -- all lanes end with full per-col max
    #pragma unroll
    for (int q = 0; q < 8; q++){
      float v = mxv[q];
      v = fmaxf(v, __shfl_xor(v, 16, 64));
      v = fmaxf(v, __shfl_xor(v, 32, 64));
      mxv[q] = v;
    }
    if (quad == 0){
      int col = (wv << 4) + l15;
      float b2v = b2L[col];
      #pragma unroll
      for (int q = 0; q < 8; q++)
        out[(size_t)(qid0 + q) * 128 + col] = mxv[q] + b2v;
    }
  }
}

// ---------------------------------------------------------------------------
// k_tail: pos[idx], batch[idx], lframes[idx] as fp32 at flat offsets.
// ---------------------------------------------------------------------------
__global__ __launch_bounds__(256) void k_tail(const float* __restrict__ pos,
    const float* __restrict__ lfr, float* __restrict__ out){
  int q = blockIdx.x * 256 + threadIdx.x;   // 0..16383
  int b = q >> 12;
  int node = (b << 14) + ((q & 4095) << 2);
  float* o_pos = out + 2097152;    // 16384*128
  float* o_bat = out + 2146304;    // + 16384*3
  float* o_lf  = out + 2162688;    // + 16384
  #pragma unroll
  for (int j = 0; j < 3; j++) o_pos[q * 3 + j] = pos[node * 3 + j];
  o_bat[q] = (float)b;
  #pragma unroll
  for (int j = 0; j < 9; j++) o_lf[q * 9 + j] = lfr[node * 9 + j];
}

extern "C" void kernel_launch(void* const* d_in, const int* in_sizes, int n_in,
                              void* d_out, int out_size, void* d_ws, size_t ws_size,
                              hipStream_t stream){
  const float* x   = (const float*)d_in[0];
  const float* pos = (const float*)d_in[1];
  const float* lfr = (const float*)d_in[2];
  // d_in[3] = batch (recomputed analytically)
  const float* W1  = (const float*)d_in[4];
  const float* b1  = (const float*)d_in[5];
  const float* W2  = (const float*)d_in[6];
  const float* b2  = (const float*)d_in[7];

  unsigned short* kfB = (unsigned short*)d_ws;
  float* normB = (float*)((char*)d_ws + WS_NORM);
  int*   nbr   = (int*)((char*)d_ws + WS_NBR);
  float* out = (float*)d_out;

  hipLaunchKernelGGL(k_prep, dim3(256),  dim3(256),  0, stream, x, pos, lfr, kfB, normB);
  hipLaunchKernelGGL(k_knn,  dim3(256),  dim3(1024), 0, stream, kfB, normB, x, pos, lfr, nbr);
  hipLaunchKernelGGL(k_mlp,  dim3(2048), dim3(512),  0, stream, x, lfr, nbr, W1, b1, W2, b2, out);
  hipLaunchKernelGGL(k_tail, dim3(64),   dim3(256),  0, stream, pos, lfr, out);
}

// Round 3
// 655.728 us; speedup vs baseline: 1.2589x; 1.0706x over previous
//
#include <hip/hip_runtime.h>
#include <hip/hip_bf16.h>

// Problem constants
#define NTOT 65536      // B*N
#define KNN  20
#define KROW 104        // bf16 kf row stride (67 dims + pad)

typedef __attribute__((ext_vector_type(4))) float f32x4;
typedef __attribute__((ext_vector_type(8))) short s16x8;

// ws layout (bytes): kfB bf16[65536][104] | normB f32[65536] | nbr i32
#define WS_NORM 13631488
#define WS_NBR  13893632

// ---- k_knn LDS map (bytes) ----
// buf: 144 rows x 257 dwords (256 columns + 1 pad for bank spread) = 148032
// col = qLocal*4 + kq   (qLocal 0..63 within block, kq = key quarter 0..3)
#define ROWS 144
#define CSTR 257
#define OFF_TAUG 149056     // unsigned tauG[64]
#define OFF_MG   149312     // unsigned mg[64*32]
#define KNN_SMEM 157504
#define THRESH 64           // compact when cntR > THRESH (max 128 <= 144 rows)

__device__ __forceinline__ unsigned short f2bf_rne(float v){
  unsigned u = __float_as_uint(v);
  return (unsigned short)((u + 0x7FFFu + ((u >> 16) & 1u)) >> 16);
}

// ---------------------------------------------------------------------------
// k_prep: kf = [s(16), R^T v(48), pos(3)] -> bf16 rows (stride 104) + f32 norm
// ---------------------------------------------------------------------------
__global__ __launch_bounds__(256) void k_prep(const float* __restrict__ x,
        const float* __restrict__ pos, const float* __restrict__ lfr,
        unsigned short* __restrict__ kfB, float* __restrict__ normB){
  int n = blockIdx.x * 256 + threadIdx.x;
  const float* xr = x + n * 64;
  float R[9];
  #pragma unroll
  for (int j = 0; j < 9; j++) R[j] = lfr[n * 9 + j];
  float c[67];
  #pragma unroll
  for (int i = 0; i < 16; i++) c[i] = xr[i];
  #pragma unroll
  for (int k = 0; k < 16; k++){
    float v0 = xr[16 + 3*k], v1 = xr[17 + 3*k], v2 = xr[18 + 3*k];
    #pragma unroll
    for (int a = 0; a < 3; a++)
      c[16 + 3*k + a] = R[a] * v0 + R[3 + a] * v1 + R[6 + a] * v2;  // R^T v
  }
  #pragma unroll
  for (int a = 0; a < 3; a++) c[64 + a] = pos[n * 3 + a];
  float sq = 0.f;
  #pragma unroll
  for (int d = 0; d < 67; d++) sq += c[d] * c[d];
  __attribute__((aligned(16))) unsigned short row[KROW];
  #pragma unroll
  for (int d = 0; d < 67; d++) row[d] = f2bf_rne(c[d]);
  #pragma unroll
  for (int d = 67; d < KROW; d++) row[d] = 0;
  uint4* dst = (uint4*)(kfB + (size_t)n * KROW);
  const uint4* s4 = (const uint4*)row;
  #pragma unroll
  for (int i = 0; i < 13; i++) dst[i] = s4[i];
  normB[n] = sq;
}

// ---------------------------------------------------------------------------
// col_compact: exact top-32 (unique 32-bit packed values) of one column with
// cn (<=128) entries. 32-round ballot binary search for the 32nd smallest,
// then ballot-prefix rewrite. Wave-local, no barriers, no LDS counters.
// ---------------------------------------------------------------------------
__device__ __forceinline__ unsigned col_compact(unsigned* buf,
    int col, int cn, int lane){
  unsigned e0 = (lane < cn) ? buf[lane * CSTR + col] : 0xFFFFFFFFu;
  unsigned e1 = (lane + 64 < cn) ? buf[(lane + 64) * CSTR + col] : 0xFFFFFFFFu;
  unsigned T = 0;
  #pragma unroll 1
  for (int b = 31; b >= 0; --b){
    unsigned cand = T | (1u << b);
    int c = __popcll(__ballot(e0 < cand)) + __popcll(__ballot(e1 < cand));
    if (c <= 31) T = cand;   // largest U with count(<U)<=31  ==> 32nd smallest
  }
  unsigned long long m0 = __ballot(e0 <= T);
  unsigned long long m1 = __ballot(e1 <= T);
  int b1 = __popcll(m0);
  unsigned long long ltm = (1ull << lane) - 1ull;
  if (e0 <= T) buf[__popcll(m0 & ltm) * CSTR + col] = e0;
  if (e1 <= T) buf[(b1 + __popcll(m1 & ltm)) * CSTR + col] = e1;
  return T;
}

// ---------------------------------------------------------------------------
// k_knn: barrier-free scan. 256 blocks x 1024 thr (16 waves). Wave (wq,kq):
// 16 queries x 4096 keys (quarter kq). Keys direct from global (L2-resident;
// block->batch = blk&3 puts one 3.4MB batch slice per XCD). Candidate counts
// live in quad-uniform REGISTERS (columns are quad-exclusive) -> no LDS
// atomics/reads in the hot path. 4-slot register prefetch pipeline.
// Shared monotone tau via atomicMin(tauG), refreshed once per 4 groups.
// ---------------------------------------------------------------------------
__global__ __launch_bounds__(1024, 4) void k_knn(
    const unsigned short* __restrict__ kfB, const float* __restrict__ normB,
    const float* __restrict__ x, const float* __restrict__ pos,
    const float* __restrict__ lfr, int* __restrict__ nbr){
  __shared__ __attribute__((aligned(16))) char smem[KNN_SMEM];
  unsigned* buf = (unsigned*)smem;
  unsigned* tauG = (unsigned*)(smem + OFF_TAUG);
  unsigned* mg = (unsigned*)(smem + OFF_MG);

  int tid = threadIdx.x;
  int blk = blockIdx.x;
  int b = blk & 3;                 // batch; XCD (blk%8) serves one batch slice
  int qloc0 = (blk >> 2) << 6;     // query block within batch: 0..4032
  int bbase = b << 14;

  if (tid < 64) tauG[tid] = 0x7F7FC000u;   // huge float (not NaN)

  int lane = tid & 63;
  int wv = tid >> 6;               // 0..15
  int wq = wv >> 2;                // query sub-group 0..3
  int kq = wv & 3;                 // key quarter 0..3
  int l15 = lane & 15, quad = lane >> 4;
  int colB = (wq << 6) + kq;       // col = colB + quad*16 + r*4

  // A fragments: wave's 16 queries
  int qloc = qloc0 + (wq << 4);
  s16x8 af[3];
  {
    int nodeA = bbase + ((qloc + l15) << 2);
    const unsigned short* ap = kfB + (size_t)nodeA * KROW + quad * 8;
    af[0] = *(const s16x8*)(ap);
    af[1] = *(const s16x8*)(ap + 32);
    af[2] = *(const s16x8*)(ap + 64);
  }
  float qsq[4];
  #pragma unroll
  for (int r = 0; r < 4; r++)
    qsq[r] = normB[bbase + ((qloc + (quad << 2) + r) << 2)];

  float tauR[4] = {3.0e38f, 3.0e38f, 3.0e38f, 3.0e38f};
  int cntR[4];                     // quad-uniform per-column counts (registers)

  // key stream pointers (lane l15 -> key (kq*4096 + g*16 + l15))
  const unsigned short* kp = kfB + (size_t)(bbase + (kq << 12) + l15) * KROW + quad * 8;
  const float* np = normB + (bbase + (kq << 12) + l15);

  __syncthreads();   // tauG init visible

  s16x8 cK[4][3];
  float nK[4];
  #define LOADK(S) do { \
      cK[S][0] = *(const s16x8*)(kp); \
      cK[S][1] = *(const s16x8*)(kp + 32); \
      cK[S][2] = *(const s16x8*)(kp + 64); \
      nK[S] = *np; kp += 16 * KROW; np += 16; } while (0)

  auto comp = [&](const s16x8 bf[3], float ksqv, float d2v[4]){
    f32x4 acc = (f32x4){0.f, 0.f, 0.f, 0.f};
    acc = __builtin_amdgcn_mfma_f32_16x16x32_bf16(af[0], bf[0], acc, 0, 0, 0);
    acc = __builtin_amdgcn_mfma_f32_16x16x32_bf16(af[1], bf[1], acc, 0, 0, 0);
    acc = __builtin_amdgcn_mfma_f32_16x16x32_bf16(af[2], bf[2], acc, 0, 0, 0);
    #pragma unroll
    for (int r = 0; r < 4; r++)
      d2v[r] = fmaxf(qsq[r] + ksqv - 2.f * acc[r], 0.f);
  };

  auto seed = [&](const float d2v[4], int g){
    int kidx = (kq << 12) + (g << 4) + l15;
    #pragma unroll
    for (int r = 0; r < 4; r++){
      unsigned pk = ((__float_as_uint(d2v[r]) + 0x2000u) & 0xFFFFC000u) | (unsigned)kidx;
      buf[((g << 4) + l15) * CSTR + colB + (quad << 4) + (r << 2)] = pk;
    }
  };

  auto process = [&](const float d2v[4], int g){
    bool p[4];
    #pragma unroll
    for (int r = 0; r < 4; r++) p[r] = d2v[r] < tauR[r];
    if (__any(p[0] | p[1] | p[2] | p[3])){
      int kidx = (kq << 12) + (g << 4) + l15;
      #pragma unroll
      for (int r = 0; r < 4; r++){
        unsigned long long m = __ballot(p[r]);
        if (m){
          int lo = (int)((m >> (quad << 4)) & 0xFFFFull);
          if (lo){
            int colr = colB + (quad << 4) + (r << 2);
            int pre = __popc(lo & ((1 << l15) - 1));
            if (p[r]){
              unsigned pk = ((__float_as_uint(d2v[r]) + 0x2000u) & 0xFFFFC000u) | (unsigned)kidx;
              buf[(cntR[r] + pre) * CSTR + colr] = pk;
            }
            cntR[r] += __popc(lo);      // quad-uniform update, no atomics
          }
        }
      }
    }
  };

  // compact any over-limit column (wave-cooperative), update tauG, refresh tau
  auto check_compact = [&](int limit){
    #pragma unroll
    for (int r = 0; r < 4; r++){
      unsigned long long mr = __ballot(cntR[r] > limit);
      while (mr){
        int ldr = __ffsll((unsigned long long)mr) - 1;
        int qd = ldr >> 4;
        mr &= ~(0xFFFFull << (qd << 4));
        int col = colB + (qd << 4) + (r << 2);
        int cn = __shfl(cntR[r], qd << 4, 64);
        unsigned T = col_compact(buf, col, cn, lane);
        if (quad == qd) cntR[r] = 32;
        if (lane == 0) atomicMin(&tauG[(wq << 4) + (qd << 2) + r], T);
      }
    }
  };

  // ---- prologue: fill 4 slots, seed groups 0..3 unconditionally ----
  float d2v[4];
  LOADK(0); LOADK(1); LOADK(2); LOADK(3);    // g0..g3
  #pragma unroll
  for (int j = 0; j < 4; j++){
    comp(cK[j], nK[j], d2v);
    seed(d2v, j);
    LOADK(j);                                 // prefetch g4..g7
  }
  #pragma unroll
  for (int r = 0; r < 4; r++) cntR[r] = 64;

  // ---- main scan: 4 groups/iter, 4-deep register prefetch ----
  #pragma unroll 1
  for (int g = 4; g < 256; g += 4){
    #pragma unroll
    for (int j = 0; j < 4; j++){
      comp(cK[j], nK[j], d2v);
      LOADK(j);                               // prefetch g+4+j (tail overruns into valid ws)
      process(d2v, g + j);
    }
    check_compact(THRESH);
    uint4 tg = *(const uint4*)&tauG[(wq << 4) + (quad << 2)];
    tauR[0] = __uint_as_float(tg.x & 0xFFFFC000u);
    tauR[1] = __uint_as_float(tg.y & 0xFFFFC000u);
    tauR[2] = __uint_as_float(tg.z & 0xFFFFC000u);
    tauR[3] = __uint_as_float(tg.w & 0xFFFFC000u);
  }

  // ---- final per-column exact top-32 (every column ends at exactly 32) ----
  check_compact(32);
  __syncthreads();

  // ---- per-query merge of 4 columns (4x32 = 128 fixed) -> top-32 into mg ----
  #pragma unroll 1
  for (int s = 0; s < 4; s++){
    int q = (wv << 2) + s;           // 0..63
    unsigned e0 = buf[(lane & 31) * CSTR + (q << 2) + (lane >> 5)];
    unsigned e1 = buf[(lane & 31) * CSTR + (q << 2) + 2 + (lane >> 5)];
    unsigned T = 0;
    #pragma unroll 1
    for (int bb = 31; bb >= 0; --bb){
      unsigned cand = T | (1u << bb);
      int c = __popcll(__ballot(e0 < cand)) + __popcll(__ballot(e1 < cand));
      if (c <= 31) T = cand;
    }
    unsigned long long m0 = __ballot(e0 <= T);
    unsigned long long m1 = __ballot(e1 <= T);
    int b1 = __popcll(m0);
    unsigned long long ltm = (1ull << lane) - 1ull;
    int p0 = __popcll(m0 & ltm);
    int p1 = b1 + __popcll(m1 & ltm);
    if ((e0 <= T) && (p0 < 32)) mg[(q << 5) + p0] = e0;
    if ((e1 <= T) && (p1 < 32)) mg[(q << 5) + p1] = e1;
  }
  __syncthreads();

  // ---- fp64 exact rerank of 32 candidates/query (overlays buf region) ----
  double* qkf = (double*)(smem);
  double* rrD = (double*)(smem + 34304);
  int*    rrI = (int*)(smem + 50688);

  {
    int t16 = tid & 15, q = tid >> 4;
    int node = bbase + ((qloc0 + q) << 2);
    const float* xr = x + node * 64;
    for (int dd = t16; dd < 67; dd += 16){
      double val;
      if (dd < 16) val = (double)xr[dd];
      else if (dd < 64){
        int r = dd - 16; int k = r / 3; int a = r - 3 * k;
        val = (double)lfr[node*9 + a]     * (double)xr[16 + 3*k]
            + (double)lfr[node*9 + 3 + a] * (double)xr[17 + 3*k]
            + (double)lfr[node*9 + 6 + a] * (double)xr[18 + 3*k];
      } else val = (double)pos[node*3 + (dd - 64)];
      qkf[q * 67 + dd] = val;
    }
  }
  __syncthreads();
  {
    int t16 = tid & 15, q = tid >> 4;
    for (int j = t16; j < 32; j += 16){
      int idx = (int)(mg[(q << 5) + j] & 0x3FFFu);
      int node = bbase + idx;
      const float* xr = x + node * 64;
      double R[9];
      #pragma unroll
      for (int t = 0; t < 9; t++) R[t] = (double)lfr[node * 9 + t];
      double d2 = 0.0;
      #pragma unroll
      for (int dd = 0; dd < 16; dd++){ double t = (double)xr[dd] - qkf[q*67 + dd]; d2 += t * t; }
      #pragma unroll
      for (int k = 0; k < 16; k++){
        double v0 = xr[16 + 3*k], v1 = xr[17 + 3*k], v2 = xr[18 + 3*k];
        #pragma unroll
        for (int a = 0; a < 3; a++){
          double val = R[a] * v0 + R[3 + a] * v1 + R[6 + a] * v2;
          double t = val - qkf[q*67 + 16 + 3*k + a]; d2 += t * t;
        }
      }
      #pragma unroll
      for (int a = 0; a < 3; a++){ double t = (double)pos[node*3 + a] - qkf[q*67 + 64 + a]; d2 += t * t; }
      rrD[q * 32 + j] = d2; rrI[q * 32 + j] = idx;
    }
  }
  __syncthreads();
  if (tid < 64){
    int qq = tid;
    int qid = (b << 12) + qloc0 + qq;
    #pragma unroll 1
    for (int s = 0; s < KNN; s++){
      double best = rrD[qq * 32 + s]; int bi = s;
      for (int t = s + 1; t < 32; t++){
        double v = rrD[qq * 32 + t]; if (v < best){ best = v; bi = t; }
      }
      double tv = rrD[qq * 32 + bi]; rrD[qq * 32 + bi] = rrD[qq * 32 + s]; rrD[qq * 32 + s] = tv;
      int ti = rrI[qq * 32 + bi]; rrI[qq * 32 + bi] = rrI[qq * 32 + s]; rrI[qq * 32 + s] = ti;
      nbr[qid * KNN + s] = bbase + rrI[qq * 32 + s];
    }
  }
}

// ---------------------------------------------------------------------------
// k_mlp (MFMA rewrite): 8 queries/block = 160 edge-rows (10 m-tiles), 512 thr
// (8 waves, wave wv owns 16 output cols). bf16 MFMA both layers, fp32 acc.
// LDS k-blocked layouts [k/32][row][32] (16B-aligned b128 frags, 2-way banks).
// Max-over-20-edges fully in registers via compile-time query-boundary masks.
// ---------------------------------------------------------------------------
#define M_X   0         // xs f32[160][68] = 43520 ; later Wt2 bf16[4][128][32]
#define M_H   43520     // hB bf16[4][160][32] = 40960
#define M_A1  84480     // a1B bf16[4][160][32] = 40960 (early: nbrL/xdL/lfL overlay)
#define M_W   125440    // Wt1 bf16[4][128][32] = 32768
#define M_B1  158208    // b1 f32[128]
#define M_B2  158720    // b2 f32[128]
#define M_SZ  159232

__global__ __launch_bounds__(512) void k_mlp(const float* __restrict__ x,
    const float* __restrict__ lfr, const int* __restrict__ nbr,
    const float* __restrict__ W1, const float* __restrict__ b1,
    const float* __restrict__ W2, const float* __restrict__ b2,
    float* __restrict__ out){
  __shared__ __attribute__((aligned(16))) char smem[M_SZ];
  float* xsF = (float*)(smem + M_X);
  unsigned short* hB = (unsigned short*)(smem + M_H);
  unsigned short* a1B = (unsigned short*)(smem + M_A1);
  unsigned short* wt1 = (unsigned short*)(smem + M_W);
  unsigned short* wt2 = (unsigned short*)(smem + M_X);
  float* b1L = (float*)(smem + M_B1);
  float* b2L = (float*)(smem + M_B2);
  int*   nbrL = (int*)(smem + M_A1);            // overlay (dead before a1 writes)
  float* xdL  = (float*)(smem + M_A1 + 640);    // 8x64 f32
  float* lfL  = (float*)(smem + M_A1 + 2688);   // 8x9 f32

  int tid = threadIdx.x;
  int qid0 = blockIdx.x * 8;
  int lane = tid & 63, wv = tid >> 6;
  int l15 = lane & 15, quad = lane >> 4;

  // ---- init loads ----
  if (tid < 160) nbrL[tid] = nbr[qid0 * 20 + tid];
  {
    int q = tid >> 6, d = tid & 63;
    int qid = qid0 + q;
    int node = ((qid >> 12) << 14) + ((qid & 4095) << 2);
    xdL[q * 64 + d] = x[node * 64 + d];
  }
  if (tid < 72){
    int q = tid / 9, j = tid - 9 * q;
    int qid = qid0 + q;
    int node = ((qid >> 12) << 14) + ((qid & 4095) << 2);
    lfL[q * 9 + j] = lfr[node * 9 + j];
  }
  if (tid < 128){ b1L[tid] = b1[tid]; b2L[tid] = b2[tid]; }
  __syncthreads();

  // ---- gather x_src into xs (160 rows x 64 f32, stride 68) ----
  {
    int f4 = tid & 15;
    #pragma unroll
    for (int p = 0; p < 5; p++){
      int e = (tid >> 4) + (p << 5);
      float4 v = *(const float4*)&x[(size_t)nbrL[e] * 64 + (f4 << 2)];
      *(float4*)&xsF[e * 68 + (f4 << 2)] = v;
    }
  }
  __syncthreads();

  // ---- build h bf16 into hB [d>>5][e][d&31] ----
  {
    int d = tid & 127, eo = tid >> 7;   // eo 0..3
    int cls, kk = 0, aa = 0;
    if (d < 64) cls = 0;
    else { int dd = d - 64;
      if (dd < 16) cls = 1;
      else { cls = 2; int r = dd - 16; kk = (r * 21846) >> 16; aa = r - 3 * kk; } }
    int hoff = ((d >> 5) * 160) * 32 + (d & 31);
    #pragma unroll 4
    for (int p = 0; p < 40; p++){
      int e = eo + (p << 2);
      int q = (e * 3277) >> 16;       // e/20 for e<160
      float v;
      if (cls == 0) v = xdL[q * 64 + d];
      else if (cls == 1) v = xsF[e * 68 + (d - 64)] - xdL[q * 64 + (d - 64)];
      else {
        int base = 16 + 3 * kk;
        float u0 = xsF[e * 68 + base]     - xdL[q * 64 + base];
        float u1 = xsF[e * 68 + base + 1] - xdL[q * 64 + base + 1];
        float u2 = xsF[e * 68 + base + 2] - xdL[q * 64 + base + 2];
        v = lfL[q * 9 + aa * 3] * u0 + lfL[q * 9 + aa * 3 + 1] * u1 + lfL[q * 9 + aa * 3 + 2] * u2;
      }
      hB[hoff + e * 32] = f2bf_rne(v);
    }
  }
  __syncthreads();   // hB done; xs/xdL/lfL/nbrL dead

  // ---- stage Wt1 -> M_W, Wt2 -> M_X  (layout [k>>5][n][32], value W[k][n]) ----
  #pragma unroll 4
  for (int i = tid; i < 16384; i += 512){
    int k = i >> 7, n = i & 127;
    int a = ((k >> 5) * 128 + n) * 32 + (k & 31);
    wt1[a] = f2bf_rne(W1[i]);
    wt2[a] = f2bf_rne(W2[i]);
  }
  __syncthreads();   // weights visible

  // ---- layer 1: a1 = relu(h @ W1 + b1) ----
  {
    s16x8 bfr[4];
    #pragma unroll
    for (int ks = 0; ks < 4; ks++)
      bfr[ks] = *(const s16x8*)(wt1 + ((ks * 128 + (wv << 4) + l15) * 32 + (quad << 3)));
    float b1v = b1L[(wv << 4) + l15];
    int colhi = wv >> 1, collo = ((wv & 1) << 4) + l15;
    #pragma unroll
    for (int mt = 0; mt < 10; mt++){
      f32x4 acc = (f32x4){0.f, 0.f, 0.f, 0.f};
      #pragma unroll
      for (int ks = 0; ks < 4; ks++){
        s16x8 af = *(const s16x8*)(hB + ((ks * 160 + (mt << 4) + l15) * 32 + (quad << 3)));
        acc = __builtin_amdgcn_mfma_f32_16x16x32_bf16(af, bfr[ks], acc, 0, 0, 0);
      }
      #pragma unroll
      for (int r = 0; r < 4; r++){
        float v = fmaxf(acc[r] + b1v, 0.f);
        int row = (mt << 4) + (quad << 2) + r;
        a1B[(colhi * 160 + row) * 32 + collo] = f2bf_rne(v);
      }
    }
  }
  __syncthreads();   // a1 complete

  // ---- layer 2 + max over edges (registers only) ----
  {
    s16x8 bfr[4];
    #pragma unroll
    for (int ks = 0; ks < 4; ks++)
      bfr[ks] = *(const s16x8*)(wt2 + ((ks * 128 + (wv << 4) + l15) * 32 + (quad << 3)));
    float mxv[8];
    #pragma unroll
    for (int q = 0; q < 8; q++) mxv[q] = -3.0e38f;
    const int QA[10]  = {0,0,1,2,3,4,4,5,6,7};
    const int CUT[10] = {16,4,8,12,16,16,4,8,12,16};
    #pragma unroll
    for (int mt = 0; mt < 10; mt++){
      f32x4 acc = (f32x4){0.f, 0.f, 0.f, 0.f};
      #pragma unroll
      for (int ks = 0; ks < 4; ks++){
        s16x8 af = *(const s16x8*)(a1B + ((ks * 160 + (mt << 4) + l15) * 32 + (quad << 3)));
        acc = __builtin_amdgcn_mfma_f32_16x16x32_bf16(af, bfr[ks], acc, 0, 0, 0);
      }
      int qa = QA[mt], cut = CUT[mt];
      if (cut >= 16){
        #pragma unroll
        for (int r = 0; r < 4; r++) mxv[qa] = fmaxf(mxv[qa], acc[r]);
      } else {
        #pragma unroll
        for (int r = 0; r < 4; r++){
          int lr = (quad << 2) + r;
          bool toA = lr < cut;
          mxv[qa]     = fmaxf(mxv[qa],     toA ? acc[r] : -3.0e38f);
          mxv[qa + 1] = fmaxf(mxv[qa + 1], toA ? -3.0e38f : acc[r]);
        }
      }
    }
    // combine across quads (rows) -- all lanes end with full per-col max
    #pragma unroll
    for (int q = 0; q < 8; q++){
      float v = mxv[q];
      v = fmaxf(v, __shfl_xor(v, 16, 64));
      v = fmaxf(v, __shfl_xor(v, 32, 64));
      mxv[q] = v;
    }
    if (quad == 0){
      int col = (wv << 4) + l15;
      float b2v = b2L[col];
      #pragma unroll
      for (int q = 0; q < 8; q++)
        out[(size_t)(qid0 + q) * 128 + col] = mxv[q] + b2v;
    }
  }
}

// ---------------------------------------------------------------------------
// k_tail: pos[idx], batch[idx], lframes[idx] as fp32 at flat offsets.
// ---------------------------------------------------------------------------
__global__ __launch_bounds__(256) void k_tail(const float* __restrict__ pos,
    const float* __restrict__ lfr, float* __restrict__ out){
  int q = blockIdx.x * 256 + threadIdx.x;   // 0..16383
  int b = q >> 12;
  int node = (b << 14) + ((q & 4095) << 2);
  float* o_pos = out + 2097152;    // 16384*128
  float* o_bat = out + 2146304;    // + 16384*3
  float* o_lf  = out + 2162688;    // + 16384
  #pragma unroll
  for (int j = 0; j < 3; j++) o_pos[q * 3 + j] = pos[node * 3 + j];
  o_bat[q] = (float)b;
  #pragma unroll
  for (int j = 0; j < 9; j++) o_lf[q * 9 + j] = lfr[node * 9 + j];
}

extern "C" void kernel_launch(void* const* d_in, const int* in_sizes, int n_in,
                              void* d_out, int out_size, void* d_ws, size_t ws_size,
                              hipStream_t stream){
  const float* x   = (const float*)d_in[0];
  const float* pos = (const float*)d_in[1];
  const float* lfr = (const float*)d_in[2];
  // d_in[3] = batch (recomputed analytically)
  const float* W1  = (const float*)d_in[4];
  const float* b1  = (const float*)d_in[5];
  const float* W2  = (const float*)d_in[6];
  const float* b2  = (const float*)d_in[7];

  unsigned short* kfB = (unsigned short*)d_ws;
  float* normB = (float*)((char*)d_ws + WS_NORM);
  int*   nbr   = (int*)((char*)d_ws + WS_NBR);
  float* out = (float*)d_out;

  hipLaunchKernelGGL(k_prep, dim3(256),  dim3(256),  0, stream, x, pos, lfr, kfB, normB);
  hipLaunchKernelGGL(k_knn,  dim3(256),  dim3(1024), 0, stream, kfB, normB, x, pos, lfr, nbr);
  hipLaunchKernelGGL(k_mlp,  dim3(2048), dim3(512),  0, stream, x, lfr, nbr, W1, b1, W2, b2, out);
  hipLaunchKernelGGL(k_tail, dim3(64),   dim3(256),  0, stream, pos, lfr, out);
}